// Round 19
// baseline (50.186 us; speedup 1.0000x reference)
//
#include <hip/hip_runtime.h>
#include <math.h>

#define NTOK 16384
#define DK   2048
#define NEXP 64

typedef float f32x4 __attribute__((ext_vector_type(4)));
typedef int   i32x4 __attribute__((ext_vector_type(4)));
typedef short s16x8 __attribute__((ext_vector_type(8)));

// ---- scalar RTNE fp32->bf16 ----
__device__ __forceinline__ unsigned short f2bf(float f) {
    union { float f; unsigned u; } v; v.f = f;
    unsigned r = (v.u + 0x7FFFu + ((v.u >> 16) & 1u)) >> 16;
    return (unsigned short)r;
}
__device__ __forceinline__ float bf2f(unsigned short h) {
    union { unsigned u; float f; } v; v.u = ((unsigned)h) << 16;
    return v.f;
}

// Pre-kernel: 3-way bf16 split of W, packed in MFMA B-fragment order by
// GLOBAL K32-round R: ws[R][n][p][lane][8 shorts], lane = g*16+rr holds
// expert 16n+rr, k = R*32+g*8..+8, plane p. 1 KB contiguous per frag.
__global__ __launch_bounds__(256) void wsplit_pack(const float* __restrict__ Wg,
                                                   unsigned short* __restrict__ ws) {
    const int t  = blockIdx.x * 256 + threadIdx.x;
    const int e  = t >> 8;
    const int k  = (t & 255) * 8;
    const int R  = k >> 5;
    const int g  = (k >> 3) & 3;
    const int rr = e & 15;
    const int n  = e >> 4;
    const int lane = g * 16 + rr;

    const float* src = Wg + (size_t)e * DK + k;
    unsigned short p0[8], p1[8], p2[8];
    #pragma unroll
    for (int j = 0; j < 8; ++j) {
        const float f = src[j];
        p0[j] = f2bf(f);  const float r1 = f - bf2f(p0[j]);
        p1[j] = f2bf(r1); const float r2 = r1 - bf2f(p1[j]);
        p2[j] = f2bf(r2);
    }
    const size_t base = (((size_t)R * 4 + n) * 3) * 512 + (size_t)lane * 8;
    *(s16x8*)(ws + base)        = *(s16x8*)p0;
    *(s16x8*)(ws + base + 512)  = *(s16x8*)p1;
    *(s16x8*)(ws + base + 1024) = *(s16x8*)p2;
}

// Async global->LDS, 16B/lane (dst wave-uniform; HW adds lane*16).
__device__ __forceinline__ void gload_lds16(const float* src, float* dst) {
    __builtin_amdgcn_global_load_lds(
        (const __attribute__((address_space(1))) void*)src,
        (__attribute__((address_space(3))) void*)dst, 16, 0, 0);
}

__device__ __forceinline__ unsigned cvtpk(float lo, float hi) {
    unsigned r;
    asm("v_cvt_pk_bf16_f32 %0, %1, %2" : "=v"(r) : "v"(lo), "v"(hi));
    return r;
}

#define SPLIT2(F0, F1, O0, O1, O2) { \
    const unsigned q0 = cvtpk((F0), (F1)); \
    const float s0 = (F0) - __builtin_bit_cast(float, q0 << 16); \
    const float s1 = (F1) - __builtin_bit_cast(float, q0 & 0xFFFF0000u); \
    const unsigned q1 = cvtpk(s0, s1); \
    const float t0 = s0 - __builtin_bit_cast(float, q1 << 16); \
    const float t1 = s1 - __builtin_bit_cast(float, q1 & 0xFFFF0000u); \
    O0 = (int)q0; O1 = (int)q1; O2 = (int)cvtpk(t0, t1); }

// x staging (coalesced + XOR bank-swizzle, both-sides involution, r15):
// 4 instrs cover the wave's [32 tok][32 k] round-chunk, dense 128B rows.
#define STAGE_X(c, BUF) { \
    _Pragma("unroll") for (int it = 0; it < 4; ++it) \
        gload_lds16(xsrc + (size_t)it * 8 * DK + (size_t)(c) * 32, \
                    &xs[w][BUF][it * 256]); }

// B: plain C loads from the packed layout (contiguous 1 KB per frag),
// issued and consumed in-phase. No register prefetch -- its L2 latency is
// covered by 4-way wave TLP (the round-19 bet), not ILP.
#define ISSUE_B(BS, R) { \
    _Pragma("unroll") for (int n = 0; n < 4; ++n) \
        _Pragma("unroll") for (int p = 0; p < 3; ++p) \
            BS[n][p] = *(const i32x4*)(wbase + ((size_t)(R) * 12 + n * 3 + p) * 512); }

// A-frags from LDS with the inverse swizzle on the granule slot.
#define CONV_LDS(BUF) { \
    _Pragma("unroll") for (int m = 0; m < 2; ++m) { \
        const int row = rr + 16 * m; \
        const int sw  = row & 7; \
        const float4 xa0 = *(const float4*)&xs[w][BUF][row * 32 + (((g * 2 + 0) ^ sw) << 2)]; \
        const float4 xa1 = *(const float4*)&xs[w][BUF][row * 32 + (((g * 2 + 1) ^ sw) << 2)]; \
        SPLIT2(xa0.x, xa0.y, A[m][0].x, A[m][1].x, A[m][2].x); \
        SPLIT2(xa0.z, xa0.w, A[m][0].y, A[m][1].y, A[m][2].y); \
        SPLIT2(xa1.x, xa1.y, A[m][0].z, A[m][1].z, A[m][2].z); \
        SPLIT2(xa1.z, xa1.w, A[m][0].w, A[m][1].w, A[m][2].w); } }

#define MFMA_TERM(pa, pb, BS) { \
    _Pragma("unroll") for (int m = 0; m < 2; ++m) \
        _Pragma("unroll") for (int n = 0; n < 4; ++n) \
            acc[m][n] = __builtin_amdgcn_mfma_f32_16x16x32_bf16( \
                __builtin_bit_cast(s16x8, A[m][pa]), \
                __builtin_bit_cast(s16x8, BS[n][pb]), acc[m][n], 0, 0, 0); }

// 6 terms: (0,0),(0,1),(1,0),(1,1),(0,2),(2,0) -> logit exact to ~2^-24 rel
#define MFMA_ALL(BS) \
    MFMA_TERM(0, 0, BS) MFMA_TERM(0, 1, BS) MFMA_TERM(1, 0, BS) \
    MFMA_TERM(1, 1, BS) MFMA_TERM(0, 2, BS) MFMA_TERM(2, 0, BS)

// Phase: issue B(c); manual vmcnt retires X(c) (gload_lds->ds_read dep is
// NOT compiler-tracked); compiler auto-inserts waits for the B register
// loads before their MFMA uses. X(c+2) staged at phase end (2-deep).
#define PHASE(c, NCNT, DO_X) { \
    ISSUE_B(BS, R0 + (c)); \
    asm volatile("s_waitcnt vmcnt(" #NCNT ")" ::: "memory"); \
    __builtin_amdgcn_sched_barrier(0); \
    CONV_LDS((c) & 1); \
    MFMA_ALL(BS); \
    if (DO_X) STAGE_X((c) + 2, (c) & 1); \
    __builtin_amdgcn_sched_barrier(0); }

// 512-thr block = 8 waves; wave w owns K-eighth (8 x K32 rounds) of the
// block's 32 tokens. Grid 512 -> 2 blocks/CU x 8 waves = 4 waves/SIMD
// (2x the r11-r17 occupancy; the only lever that has ever moved the
// latency-bound plateau: r9->r11 was 87->51 us from 1->2 waves/SIMD).
// 4 waves/SIMD requires VGPR<=128: peak demand ~110 (acc32+B48+A12+addr).
__global__ __launch_bounds__(512, 4) void topk_router_kernel(
    const float* __restrict__ x,            // [NTOK][DK] fp32
    const unsigned short* __restrict__ ws,  // packed B frags (768 KB)
    float* __restrict__ out)                // [NTOK*2] idx (as float) ++ [NTOK*2] w
{
    // xs: [8 waves][2 bufs][32x32] = 64 KB; lg overlays after the barrier:
    // [8][32][65] = 66.6 KB. smem = 16640 floats -> 2 blocks/CU by LDS.
    __shared__ float smem[16640];
    float (*xs)[2][1024] = (float (*)[2][1024])smem;

    const int tid  = threadIdx.x;
    const int w    = tid >> 6;              // wave 0..7 == K-eighth
    const int lane = tid & 63;
    const int rr   = lane & 15;
    const int g    = lane >> 4;
    const int tok0 = blockIdx.x * 32;
    const int R0   = w * 8;                 // global K32-round base

    const int lt = lane >> 3;
    const int lq = lane & 7;
    const float* xsrc = x + (size_t)(tok0 + lt) * DK + w * 256 + ((lq ^ lt) * 4);
    const unsigned short* wbase = ws + (size_t)lane * 8;

    f32x4 acc[2][4];
    #pragma unroll
    for (int m = 0; m < 2; ++m)
        #pragma unroll
        for (int n = 0; n < 4; ++n) acc[m][n] = (f32x4){0.f, 0.f, 0.f, 0.f};

    i32x4 BS[4][3];
    i32x4 A[2][3];

    // ---- prologue: X(0), X(1) in flight (4 gload_lds each) ----
    STAGE_X(0, 0);
    STAGE_X(1, 1);

    // ---- 8 phases. Outstanding at wait (FIFO): [X(c), X(c+1), B(c)] = 20
    // -> vmcnt(16) retires X(c). Tail: phase 6 same; phase 7: [X7,B7] ->
    // vmcnt(12) retires X7. ----
    PHASE(0, 16, 1);
    PHASE(1, 16, 1);
    PHASE(2, 16, 1);
    PHASE(3, 16, 1);
    PHASE(4, 16, 1);
    PHASE(5, 16, 1);
    PHASE(6, 16, 0);
    PHASE(7, 12, 0);

    // ---- combine 8 K-eighths in LDS ----
    __syncthreads();
    {
        float* lg = smem;   // [8][32][65] overlay
        #pragma unroll
        for (int m = 0; m < 2; ++m)
            #pragma unroll
            for (int n = 0; n < 4; ++n)
                #pragma unroll
                for (int r = 0; r < 4; ++r)
                    lg[(w * 32 + m * 16 + g * 4 + r) * 65 + n * 16 + rr]
                        = acc[m][n][r];
    }
    __syncthreads();

    // ---- top-2 per token: wave w -> tokens w*4..+3, lane = expert ----
    #pragma unroll 1
    for (int t = 0; t < 4; ++t) {
        const int tok = w * 4 + t;
        float v = 0.f;
        #pragma unroll
        for (int p = 0; p < 8; ++p) v += smem[(p * 32 + tok) * 65 + lane];

        // top-1 (tie -> lower index, matching lax.top_k)
        float m1 = v; int i1 = lane;
        #pragma unroll
        for (int off = 32; off > 0; off >>= 1) {
            float ov = __shfl_xor(m1, off);
            int   oi = __shfl_xor(i1, off);
            if (ov > m1 || (ov == m1 && oi < i1)) { m1 = ov; i1 = oi; }
        }
        // top-2: mask out winner
        float m2 = (lane == i1) ? -INFINITY : v; int i2 = lane;
        #pragma unroll
        for (int off = 32; off > 0; off >>= 1) {
            float ov = __shfl_xor(m2, off);
            int   oi = __shfl_xor(i2, off);
            if (ov > m2 || (ov == m2 && oi < i2)) { m2 = ov; i2 = oi; }
        }

        if (lane == 0) {
            const int gtok = tok0 + tok;
            // softmax denom cancels: w1 = 1/(1+e^{l2-l1}), w2 = 1 - w1
            const float e  = expf(m2 - m1);
            const float w1 = 1.0f / (1.0f + e);
            const float w2 = e / (1.0f + e);
            out[gtok * 2 + 0] = (float)i1;
            out[gtok * 2 + 1] = (float)i2;
            out[NTOK * 2 + gtok * 2 + 0] = w1;
            out[NTOK * 2 + gtok * 2 + 1] = w2;
        }
    }
}

extern "C" void kernel_launch(void* const* d_in, const int* in_sizes, int n_in,
                              void* d_out, int out_size, void* d_ws, size_t ws_size,
                              hipStream_t stream) {
    const float* x  = (const float*)d_in[0];
    const float* Wg = (const float*)d_in[1];
    float* out = (float*)d_out;
    unsigned short* ws = (unsigned short*)d_ws;   // 768 KB packed B
    hipLaunchKernelGGL(wsplit_pack, dim3(64), dim3(256), 0, stream, Wg, ws);
    // 512 blocks x 512 thr = 4096 waves = 4 waves/SIMD (pure-TLP design).
    hipLaunchKernelGGL(topk_router_kernel, dim3(NTOK / 32), dim3(512), 0, stream,
                       x, ws, out);
}

// Round 20
// 49.666 us; speedup vs baseline: 1.0105x; 1.0105x over previous
//
#include <hip/hip_runtime.h>
#include <math.h>

#define NTOK 16384
#define DK   2048
#define NEXP 64

typedef float f32x4 __attribute__((ext_vector_type(4)));
typedef int   i32x4 __attribute__((ext_vector_type(4)));
typedef short s16x8 __attribute__((ext_vector_type(8)));

// ---- scalar RTNE fp32->bf16 ----
__device__ __forceinline__ unsigned short f2bf(float f) {
    union { float f; unsigned u; } v; v.f = f;
    unsigned r = (v.u + 0x7FFFu + ((v.u >> 16) & 1u)) >> 16;
    return (unsigned short)r;
}
__device__ __forceinline__ float bf2f(unsigned short h) {
    union { unsigned u; float f; } v; v.u = ((unsigned)h) << 16;
    return v.f;
}

// Pre-kernel: 3-way bf16 split of W, PACKED in MFMA B-fragment order (r11):
// ws[q][c][n][p][lane][8 shorts], q = K-quarter, c = K32-round in quarter,
// lane = g*16+rr holds expert 16n+rr, k = q*512+c*32+g*8..+8, plane p.
__global__ __launch_bounds__(256) void wsplit_pack(const float* __restrict__ Wg,
                                                   unsigned short* __restrict__ ws) {
    const int t  = blockIdx.x * 256 + threadIdx.x;
    const int e  = t >> 8;
    const int k  = (t & 255) * 8;
    const int q  = k >> 9;
    const int c  = (k >> 5) & 15;
    const int g  = (k >> 3) & 3;
    const int rr = e & 15;
    const int n  = e >> 4;
    const int lane = g * 16 + rr;

    const float* src = Wg + (size_t)e * DK + k;
    unsigned short p0[8], p1[8], p2[8];
    #pragma unroll
    for (int j = 0; j < 8; ++j) {
        const float f = src[j];
        p0[j] = f2bf(f);  const float r1 = f - bf2f(p0[j]);
        p1[j] = f2bf(r1); const float r2 = r1 - bf2f(p1[j]);
        p2[j] = f2bf(r2);
    }
    const size_t base = ((((size_t)q * 16 + c) * 4 + n) * 3) * 512 + (size_t)lane * 8;
    *(s16x8*)(ws + base)        = *(s16x8*)p0;
    *(s16x8*)(ws + base + 512)  = *(s16x8*)p1;
    *(s16x8*)(ws + base + 1024) = *(s16x8*)p2;
}

// Async global->LDS, 16B/lane (dst wave-uniform; HW adds lane*16).
__device__ __forceinline__ void gload_lds16(const float* src, float* dst) {
    __builtin_amdgcn_global_load_lds(
        (const __attribute__((address_space(1))) void*)src,
        (__attribute__((address_space(3))) void*)dst, 16, 0, 0);
}

__device__ __forceinline__ unsigned cvtpk(float lo, float hi) {
    unsigned r;
    asm("v_cvt_pk_bf16_f32 %0, %1, %2" : "=v"(r) : "v"(lo), "v"(hi));
    return r;
}

#define SPLIT2(F0, F1, O0, O1, O2) { \
    const unsigned q0 = cvtpk((F0), (F1)); \
    const float s0 = (F0) - __builtin_bit_cast(float, q0 << 16); \
    const float s1 = (F1) - __builtin_bit_cast(float, q0 & 0xFFFF0000u); \
    const unsigned q1 = cvtpk(s0, s1); \
    const float t0 = s0 - __builtin_bit_cast(float, q1 << 16); \
    const float t1 = s1 - __builtin_bit_cast(float, q1 & 0xFFFF0000u); \
    O0 = (int)q0; O1 = (int)q1; O2 = (int)cvtpk(t0, t1); }

// x staging, WIDE chunks (the round-20 change): super-round = [32 tok][64 k],
// 8 gload_lds each covering 4 rows x 256 B DENSE (vs r15's 128 B) -> 2x the
// DRAM chunk size on the only HBM stream (r16 measured x at 876 GB/s = 14%
// of achievable; short strided chunks are the mechanism). Granule XOR
// swizzle (involution, rule #21): slot s of row r holds granule s^(r&15).
#define STAGE_X(s, BUF) { \
    _Pragma("unroll") for (int it = 0; it < 8; ++it) { \
        const int row = it * 4 + lt; \
        gload_lds16(xsrc + (size_t)(it * 4) * DK + (size_t)(s) * 64 \
                         + ((lgq ^ (row & 15)) * 4), \
                    &xs[w][BUF][it * 256]); } }

// B: packed frags, plain loads, issued and consumed in-phase (compiler
// inserts the waits); TLP covers the L2 latency (r19 showed this is safe).
#define ISSUE_B(BS, c) { \
    _Pragma("unroll") for (int n = 0; n < 4; ++n) \
        _Pragma("unroll") for (int p = 0; p < 3; ++p) \
            BS[n][p] = *(const i32x4*)(wbase + ((size_t)(c) * 12 + n * 3 + p) * 512); }

// A-frags for sub-round SB (0/1) from the [32][64] tile; inverse swizzle.
// row&15 == rr for both m -> sw = rr.
#define CONV_LDS(BUF, SB) { \
    _Pragma("unroll") for (int m = 0; m < 2; ++m) { \
        const int row = rr + 16 * m; \
        const float4 xa0 = *(const float4*)&xs[w][BUF][row * 64 + ((((SB) * 8 + g * 2 + 0) ^ rr) << 2)]; \
        const float4 xa1 = *(const float4*)&xs[w][BUF][row * 64 + ((((SB) * 8 + g * 2 + 1) ^ rr) << 2)]; \
        SPLIT2(xa0.x, xa0.y, A[m][0].x, A[m][1].x, A[m][2].x); \
        SPLIT2(xa0.z, xa0.w, A[m][0].y, A[m][1].y, A[m][2].y); \
        SPLIT2(xa1.x, xa1.y, A[m][0].z, A[m][1].z, A[m][2].z); \
        SPLIT2(xa1.z, xa1.w, A[m][0].w, A[m][1].w, A[m][2].w); } }

#define MFMA_TERM(pa, pb, BS) { \
    _Pragma("unroll") for (int m = 0; m < 2; ++m) \
        _Pragma("unroll") for (int n = 0; n < 4; ++n) \
            acc[m][n] = __builtin_amdgcn_mfma_f32_16x16x32_bf16( \
                __builtin_bit_cast(s16x8, A[m][pa]), \
                __builtin_bit_cast(s16x8, BS[n][pb]), acc[m][n], 0, 0, 0); }

// 6 terms: (0,0),(0,1),(1,0),(1,1),(0,2),(2,0) -> logit exact to ~2^-24 rel
#define MFMA_ALL(BS) \
    MFMA_TERM(0, 0, BS) MFMA_TERM(0, 1, BS) MFMA_TERM(1, 0, BS) \
    MFMA_TERM(1, 1, BS) MFMA_TERM(0, 2, BS) MFMA_TERM(2, 0, BS)

// Super-round s: outstanding at top (FIFO) = X(s)8 + X(s+1)8; after
// ISSUE_B = 28 -> vmcnt(20) retires X(s). Two sub-rounds per super-round.
// s=7: only X(7)8 + B 12 -> vmcnt(12) retires X(7).
#define SUPER(s, NCNT, DO_X) { \
    ISSUE_B(BS, (s) * 2); \
    asm volatile("s_waitcnt vmcnt(" #NCNT ")" ::: "memory"); \
    __builtin_amdgcn_sched_barrier(0); \
    CONV_LDS((s) & 1, 0); \
    MFMA_ALL(BS); \
    ISSUE_B(BS, (s) * 2 + 1); \
    CONV_LDS((s) & 1, 1); \
    MFMA_ALL(BS); \
    if (DO_X) STAGE_X((s) + 2, (s) & 1); \
    __builtin_amdgcn_sched_barrier(0); }

// 512-thr block = 8 waves = 2 token-groups x 4 K-quarters; 64 tok/block,
// grid 256 -> 2048 waves = 2/SIMD (same occupancy as the r15 best).
__global__ __launch_bounds__(512, 2) void topk_router_kernel(
    const float* __restrict__ x,            // [NTOK][DK] fp32
    const unsigned short* __restrict__ ws,  // packed B frags (768 KB)
    float* __restrict__ out)                // [NTOK*2] idx (as float) ++ [NTOK*2] w
{
    // xs: [8 waves][2 bufs][32 tok x 64 k] = 128 KB (1 block/CU).
    // lg overlays after the barrier: [4 kq][64 tok][65] = 16640 floats.
    __shared__ float smem[32768];
    float (*xs)[2][2048] = (float (*)[2][2048])smem;

    const int tid  = threadIdx.x;
    const int w    = tid >> 6;              // wave 0..7
    const int lane = tid & 63;
    const int tg   = w >> 2;                // token group (32 tokens)
    const int kq   = w & 3;                 // K-quarter
    const int rr   = lane & 15;
    const int g    = lane >> 4;
    const int tok0w = blockIdx.x * 64 + tg * 32;

    // staging lanes: lt = row-within-4, lgq = 16B granule within 256B row
    const int lt  = lane >> 4;              // 0..3
    const int lgq = lane & 15;              // 0..15
    const float* xsrc = x + (size_t)(tok0w + lt) * DK + kq * 512;
    const unsigned short* wbase = ws + (size_t)kq * 98304 + (size_t)lane * 8;

    f32x4 acc[2][4];
    #pragma unroll
    for (int m = 0; m < 2; ++m)
        #pragma unroll
        for (int n = 0; n < 4; ++n) acc[m][n] = (f32x4){0.f, 0.f, 0.f, 0.f};

    i32x4 BS[4][3];
    i32x4 A[2][3];

    // ---- prologue: super-rounds 0,1 staged (8 gload_lds each) ----
    STAGE_X(0, 0);
    STAGE_X(1, 1);

    // ---- 8 super-rounds (16 K32-rounds = this wave's K-quarter) ----
    SUPER(0, 20, 1);
    SUPER(1, 20, 1);
    SUPER(2, 20, 1);
    SUPER(3, 20, 1);
    SUPER(4, 20, 1);
    SUPER(5, 20, 1);
    SUPER(6, 20, 0);
    SUPER(7, 12, 0);

    // ---- combine 4 K-quarters in LDS (overlay; barrier-guarded) ----
    __syncthreads();
    {
        float* lg = smem;   // [4][64][65]
        #pragma unroll
        for (int m = 0; m < 2; ++m)
            #pragma unroll
            for (int n = 0; n < 4; ++n)
                #pragma unroll
                for (int r = 0; r < 4; ++r)
                    lg[((kq * 64) + tg * 32 + m * 16 + g * 4 + r) * 65 + n * 16 + rr]
                        = acc[m][n][r];
    }
    __syncthreads();

    // ---- top-2 per token: wave w -> tokens w*8..+7, lane = expert ----
    #pragma unroll 1
    for (int t = 0; t < 8; ++t) {
        const int tok = w * 8 + t;
        float v = 0.f;
        #pragma unroll
        for (int p = 0; p < 4; ++p) v += smem[(p * 64 + tok) * 65 + lane];

        // top-1 (tie -> lower index, matching lax.top_k)
        float m1 = v; int i1 = lane;
        #pragma unroll
        for (int off = 32; off > 0; off >>= 1) {
            float ov = __shfl_xor(m1, off);
            int   oi = __shfl_xor(i1, off);
            if (ov > m1 || (ov == m1 && oi < i1)) { m1 = ov; i1 = oi; }
        }
        // top-2: mask out winner
        float m2 = (lane == i1) ? -INFINITY : v; int i2 = lane;
        #pragma unroll
        for (int off = 32; off > 0; off >>= 1) {
            float ov = __shfl_xor(m2, off);
            int   oi = __shfl_xor(i2, off);
            if (ov > m2 || (ov == m2 && oi < i2)) { m2 = ov; i2 = oi; }
        }

        if (lane == 0) {
            const int gtok = blockIdx.x * 64 + tok;
            // softmax denom cancels: w1 = 1/(1+e^{l2-l1}), w2 = 1 - w1
            const float e  = expf(m2 - m1);
            const float w1 = 1.0f / (1.0f + e);
            const float w2 = e / (1.0f + e);
            out[gtok * 2 + 0] = (float)i1;
            out[gtok * 2 + 1] = (float)i2;
            out[NTOK * 2 + gtok * 2 + 0] = w1;
            out[NTOK * 2 + gtok * 2 + 1] = w2;
        }
    }
}

extern "C" void kernel_launch(void* const* d_in, const int* in_sizes, int n_in,
                              void* d_out, int out_size, void* d_ws, size_t ws_size,
                              hipStream_t stream) {
    const float* x  = (const float*)d_in[0];
    const float* Wg = (const float*)d_in[1];
    float* out = (float*)d_out;
    unsigned short* ws = (unsigned short*)d_ws;   // 768 KB packed B
    hipLaunchKernelGGL(wsplit_pack, dim3(64), dim3(256), 0, stream, Wg, ws);
    // 256 blocks x 512 thr = 2048 waves (2/SIMD): x staged in 256B-dense
    // chunks (2x DRAM efficiency), packed B in-phase, counted-vmcnt pipeline.
    hipLaunchKernelGGL(topk_router_kernel, dim3(NTOK / 64), dim3(512), 0, stream,
                       x, ws, out);
}

// Round 21
// 48.162 us; speedup vs baseline: 1.0420x; 1.0312x over previous
//
#include <hip/hip_runtime.h>
#include <math.h>

#define NTOK 16384
#define DK   2048
#define NEXP 64

typedef float f32x4 __attribute__((ext_vector_type(4)));
typedef int   i32x4 __attribute__((ext_vector_type(4)));
typedef short s16x8 __attribute__((ext_vector_type(8)));

// ---- scalar RTNE fp32->bf16 ----
__device__ __forceinline__ unsigned short f2bf(float f) {
    union { float f; unsigned u; } v; v.f = f;
    unsigned r = (v.u + 0x7FFFu + ((v.u >> 16) & 1u)) >> 16;
    return (unsigned short)r;
}
__device__ __forceinline__ float bf2f(unsigned short h) {
    union { unsigned u; float f; } v; v.u = ((unsigned)h) << 16;
    return v.f;
}

// Pre-kernel: 3-way bf16 split of W, packed in MFMA B-fragment order by
// GLOBAL K32-round R (r19 layout): ws[R][n][p][lane][8 shorts], lane=g*16+rr
// holds expert 16n+rr, k = R*32+g*8..+8, plane p. 1 KB contiguous per frag.
__global__ __launch_bounds__(256) void wsplit_pack(const float* __restrict__ Wg,
                                                   unsigned short* __restrict__ ws) {
    const int t  = blockIdx.x * 256 + threadIdx.x;
    const int e  = t >> 8;
    const int k  = (t & 255) * 8;
    const int R  = k >> 5;
    const int g  = (k >> 3) & 3;
    const int rr = e & 15;
    const int n  = e >> 4;
    const int lane = g * 16 + rr;

    const float* src = Wg + (size_t)e * DK + k;
    unsigned short p0[8], p1[8], p2[8];
    #pragma unroll
    for (int j = 0; j < 8; ++j) {
        const float f = src[j];
        p0[j] = f2bf(f);  const float r1 = f - bf2f(p0[j]);
        p1[j] = f2bf(r1); const float r2 = r1 - bf2f(p1[j]);
        p2[j] = f2bf(r2);
    }
    const size_t base = (((size_t)R * 4 + n) * 3) * 512 + (size_t)lane * 8;
    *(s16x8*)(ws + base)        = *(s16x8*)p0;
    *(s16x8*)(ws + base + 512)  = *(s16x8*)p1;
    *(s16x8*)(ws + base + 1024) = *(s16x8*)p2;
}

// Async global->LDS, 16B/lane (dst wave-uniform; HW adds lane*16).
__device__ __forceinline__ void gload_lds16(const float* src, float* dst) {
    __builtin_amdgcn_global_load_lds(
        (const __attribute__((address_space(1))) void*)src,
        (__attribute__((address_space(3))) void*)dst, 16, 0, 0);
}

__device__ __forceinline__ unsigned cvtpk(float lo, float hi) {
    unsigned r;
    asm("v_cvt_pk_bf16_f32 %0, %1, %2" : "=v"(r) : "v"(lo), "v"(hi));
    return r;
}

#define SPLIT2(F0, F1, O0, O1, O2) { \
    const unsigned q0 = cvtpk((F0), (F1)); \
    const float s0 = (F0) - __builtin_bit_cast(float, q0 << 16); \
    const float s1 = (F1) - __builtin_bit_cast(float, q0 & 0xFFFF0000u); \
    const unsigned q1 = cvtpk(s0, s1); \
    const float t0 = s0 - __builtin_bit_cast(float, q1 << 16); \
    const float t1 = s1 - __builtin_bit_cast(float, q1 & 0xFFFF0000u); \
    O0 = (int)q0; O1 = (int)q1; O2 = (int)cvtpk(t0, t1); }

// x staging: [64 tok][32 k] per round, 8 gload_lds x (8 rows x 128B dense).
// XOR granule swizzle (both-sides involution): slot s of row r holds global
// granule s ^ (r&7). Stage side: row&7 == lt, so source granule = lq^lt.
#define STAGE_X(c, BUF) { \
    _Pragma("unroll") for (int it = 0; it < 8; ++it) \
        gload_lds16(xsrc + (size_t)it * 8 * DK + (size_t)(c) * 32, \
                    &xs[w][BUF][it * 256]); }

// B: packed frags, plain loads, issued and consumed in-phase (compiler
// inserts the waits; TLP covers L2 latency -- r19/r20 proven safe).
#define ISSUE_B(BS, R) { \
    _Pragma("unroll") for (int n = 0; n < 4; ++n) \
        _Pragma("unroll") for (int p = 0; p < 3; ++p) \
            BS[n][p] = *(const i32x4*)(wbase + ((size_t)(R) * 12 + n * 3 + p) * 512); }

// Per-m CONV from LDS (inverse swizzle; row&7 == rr&7) -> A[3] (12 regs live)
#define CONV_M(BUF, m_) { \
    const int row_ = rr + 16 * (m_); \
    const int sw_  = rr & 7; \
    const float4 xa0 = *(const float4*)&xs[w][BUF][row_ * 32 + (((g * 2 + 0) ^ sw_) << 2)]; \
    const float4 xa1 = *(const float4*)&xs[w][BUF][row_ * 32 + (((g * 2 + 1) ^ sw_) << 2)]; \
    SPLIT2(xa0.x, xa0.y, A[0].x, A[1].x, A[2].x); \
    SPLIT2(xa0.z, xa0.w, A[0].y, A[1].y, A[2].y); \
    SPLIT2(xa1.x, xa1.y, A[0].z, A[1].z, A[2].z); \
    SPLIT2(xa1.z, xa1.w, A[0].w, A[1].w, A[2].w); }

#define MFMA1(Aa, Bb, Cc) __builtin_amdgcn_mfma_f32_16x16x32_bf16( \
    __builtin_bit_cast(s16x8, Aa), __builtin_bit_cast(s16x8, Bb), Cc, 0, 0, 0)

// 6 split-terms x 4 n for one m: (0,0),(0,1),(1,0),(1,1),(0,2),(2,0)
#define MFMA_M(m_) { \
    _Pragma("unroll") for (int n = 0; n < 4; ++n) { \
        acc[m_][n] = MFMA1(A[0], BS[n][0], acc[m_][n]); \
        acc[m_][n] = MFMA1(A[0], BS[n][1], acc[m_][n]); \
        acc[m_][n] = MFMA1(A[1], BS[n][0], acc[m_][n]); \
        acc[m_][n] = MFMA1(A[1], BS[n][1], acc[m_][n]); \
        acc[m_][n] = MFMA1(A[0], BS[n][2], acc[m_][n]); \
        acc[m_][n] = MFMA1(A[2], BS[n][0], acc[m_][n]); } }

// Round: outstanding at wait (FIFO) = X(c)8 + X(c+1)8 + B12 -> vmcnt(20)
// retires X(c). Per-m CONV->MFMA keeps A at 12 regs (acc64+B48+A12 ~ 128).
#define ROUND(c, NCNT, DO_X) { \
    ISSUE_B(BS, R0 + (c)); \
    asm volatile("s_waitcnt vmcnt(" #NCNT ")" ::: "memory"); \
    __builtin_amdgcn_sched_barrier(0); \
    CONV_M((c) & 1, 0) MFMA_M(0) \
    CONV_M((c) & 1, 1) MFMA_M(1) \
    CONV_M((c) & 1, 2) MFMA_M(2) \
    CONV_M((c) & 1, 3) MFMA_M(3) \
    if (DO_X) STAGE_X((c) + 2, (c) & 1); \
    __builtin_amdgcn_sched_barrier(0); }

// m=4 redesign (round 21): wave = 64 tok x K-eighth -> per-wave B stream
// covers 2x the tokens, halving chip B traffic 393->197 MB. The r11-r20
// plateau tracks total delivered bytes/CU (~19 B/cyc = the m13-implied
// per-CU delivery ceiling); B is the only compressible stream.
__global__ __launch_bounds__(512, 1) void topk_router_kernel(
    const float* __restrict__ x,            // [NTOK][DK] fp32
    const unsigned short* __restrict__ ws,  // packed B frags (768 KB)
    float* __restrict__ out)                // [NTOK*2] idx (as float) ++ [NTOK*2] w
{
    // xs: [8 waves][2 bufs][64 tok x 32 k] = 128 KB; lg overlay [8][64][65]
    // = 130 KB. smem = 33280 floats -> 1 block/CU (grid 256 = 1/CU anyway).
    __shared__ float smem[33280];
    float (*xs)[2][2048] = (float (*)[2][2048])smem;

    const int tid  = threadIdx.x;
    const int w    = tid >> 6;              // wave 0..7 == K-eighth
    const int lane = tid & 63;
    const int rr   = lane & 15;
    const int g    = lane >> 4;
    const int tok0 = blockIdx.x * 64;
    const int R0   = w * 8;                 // global K32-round base

    // staging lanes: row lt (+8*it), granule lq; pre-swizzled source lq^lt
    const int lt = lane >> 3;
    const int lq = lane & 7;
    const float* xsrc = x + (size_t)(tok0 + lt) * DK + w * 256 + ((lq ^ lt) * 4);
    const unsigned short* wbase = ws + (size_t)lane * 8;

    f32x4 acc[4][4];
    #pragma unroll
    for (int m = 0; m < 4; ++m)
        #pragma unroll
        for (int n = 0; n < 4; ++n) acc[m][n] = (f32x4){0.f, 0.f, 0.f, 0.f};

    i32x4 BS[4][3];
    i32x4 A[3];

    // ---- prologue: X(0), X(1) staged (8 gload_lds each) ----
    STAGE_X(0, 0);
    STAGE_X(1, 1);

    // ---- 8 rounds (this wave's K-eighth) ----
    ROUND(0, 20, 1);
    ROUND(1, 20, 1);
    ROUND(2, 20, 1);
    ROUND(3, 20, 1);
    ROUND(4, 20, 1);
    ROUND(5, 20, 1);
    ROUND(6, 20, 0);
    ROUND(7, 12, 0);

    // ---- combine 8 K-eighths in LDS (overlay; barrier-guarded) ----
    __syncthreads();
    {
        float* lg = smem;   // [8][64][65]
        #pragma unroll
        for (int m = 0; m < 4; ++m)
            #pragma unroll
            for (int n = 0; n < 4; ++n)
                #pragma unroll
                for (int r = 0; r < 4; ++r)
                    lg[(w * 64 + m * 16 + g * 4 + r) * 65 + n * 16 + rr]
                        = acc[m][n][r];
    }
    __syncthreads();

    // ---- top-2 per token: wave w -> tokens w*8..+7, lane = expert ----
    #pragma unroll 1
    for (int t = 0; t < 8; ++t) {
        const int tok = w * 8 + t;
        float v = 0.f;
        #pragma unroll
        for (int p = 0; p < 8; ++p) v += smem[(p * 64 + tok) * 65 + lane];

        // top-1 (tie -> lower index, matching lax.top_k)
        float m1 = v; int i1 = lane;
        #pragma unroll
        for (int off = 32; off > 0; off >>= 1) {
            float ov = __shfl_xor(m1, off);
            int   oi = __shfl_xor(i1, off);
            if (ov > m1 || (ov == m1 && oi < i1)) { m1 = ov; i1 = oi; }
        }
        // top-2: mask out winner
        float m2 = (lane == i1) ? -INFINITY : v; int i2 = lane;
        #pragma unroll
        for (int off = 32; off > 0; off >>= 1) {
            float ov = __shfl_xor(m2, off);
            int   oi = __shfl_xor(i2, off);
            if (ov > m2 || (ov == m2 && oi < i2)) { m2 = ov; i2 = oi; }
        }

        if (lane == 0) {
            const int gtok = tok0 + tok;
            // softmax denom cancels: w1 = 1/(1+e^{l2-l1}), w2 = 1 - w1
            const float e  = expf(m2 - m1);
            const float w1 = 1.0f / (1.0f + e);
            const float w2 = e / (1.0f + e);
            out[gtok * 2 + 0] = (float)i1;
            out[gtok * 2 + 1] = (float)i2;
            out[NTOK * 2 + gtok * 2 + 0] = w1;
            out[NTOK * 2 + gtok * 2 + 1] = w2;
        }
    }
}

extern "C" void kernel_launch(void* const* d_in, const int* in_sizes, int n_in,
                              void* d_out, int out_size, void* d_ws, size_t ws_size,
                              hipStream_t stream) {
    const float* x  = (const float*)d_in[0];
    const float* Wg = (const float*)d_in[1];
    float* out = (float*)d_out;
    unsigned short* ws = (unsigned short*)d_ws;   // 768 KB packed B
    hipLaunchKernelGGL(wsplit_pack, dim3(64), dim3(256), 0, stream, Wg, ws);
    // 256 blocks x 512 thr = 2048 waves (2/SIMD): 64-tok waves halve the
    // B stream (393->197 MB); in-phase B, counted-vmcnt x pipeline.
    hipLaunchKernelGGL(topk_router_kernel, dim3(NTOK / 64), dim3(512), 0, stream,
                       x, ws, out);
}

// Round 23
// 47.777 us; speedup vs baseline: 1.0504x; 1.0081x over previous
//
#include <hip/hip_runtime.h>
#include <math.h>

#define NTOK 16384
#define DK   2048
#define NEXP 64

typedef float f32x4 __attribute__((ext_vector_type(4)));
typedef int   i32x4 __attribute__((ext_vector_type(4)));
typedef short s16x8 __attribute__((ext_vector_type(8)));

// ---- scalar RTNE fp32->bf16 ----
__device__ __forceinline__ unsigned short f2bf(float f) {
    union { float f; unsigned u; } v; v.f = f;
    unsigned r = (v.u + 0x7FFFu + ((v.u >> 16) & 1u)) >> 16;
    return (unsigned short)r;
}
__device__ __forceinline__ float bf2f(unsigned short h) {
    union { unsigned u; float f; } v; v.u = ((unsigned)h) << 16;
    return v.f;
}

// Pre-kernel: 3-way bf16 split of W, PACKED in MFMA B-fragment order (r11):
// ws[w][c][n][p][lane][8 shorts], lane = g*16 + rr holds expert 16n+rr,
// k = w*512 + c*32 + g*8..+8, plane p. 1 KB contiguous per (c,n,p) frag.
__global__ __launch_bounds__(256) void wsplit_pack(const float* __restrict__ Wg,
                                                   unsigned short* __restrict__ ws) {
    const int t  = blockIdx.x * 256 + threadIdx.x;  // 16384 = 64 experts x 256 k-octets
    const int e  = t >> 8;
    const int k  = (t & 255) * 8;
    const int w  = k >> 9;
    const int c  = (k >> 5) & 15;
    const int g  = (k >> 3) & 3;
    const int rr = e & 15;
    const int n  = e >> 4;
    const int lane = g * 16 + rr;

    const float* src = Wg + (size_t)e * DK + k;
    unsigned short p0[8], p1[8], p2[8];
    #pragma unroll
    for (int j = 0; j < 8; ++j) {
        const float f = src[j];
        p0[j] = f2bf(f);  const float r1 = f - bf2f(p0[j]);
        p1[j] = f2bf(r1); const float r2 = r1 - bf2f(p1[j]);
        p2[j] = f2bf(r2);
    }
    const size_t base = ((((size_t)w * 16 + c) * 4 + n) * 3) * 512 + (size_t)lane * 8;
    *(s16x8*)(ws + base)        = *(s16x8*)p0;
    *(s16x8*)(ws + base + 512)  = *(s16x8*)p1;
    *(s16x8*)(ws + base + 1024) = *(s16x8*)p2;
}

// Async global->LDS, 16B/lane (dst wave-uniform; HW adds lane*16).
__device__ __forceinline__ void gload_lds16(const float* src, float* dst) {
    __builtin_amdgcn_global_load_lds(
        (const __attribute__((address_space(1))) void*)src,
        (__attribute__((address_space(3))) void*)dst, 16, 0, 0);
}

__device__ __forceinline__ unsigned cvtpk(float lo, float hi) {
    unsigned r;
    asm("v_cvt_pk_bf16_f32 %0, %1, %2" : "=v"(r) : "v"(lo), "v"(hi));
    return r;
}

#define SPLIT2(F0, F1, O0, O1, O2) { \
    const unsigned q0 = cvtpk((F0), (F1)); \
    const float s0 = (F0) - __builtin_bit_cast(float, q0 << 16); \
    const float s1 = (F1) - __builtin_bit_cast(float, q0 & 0xFFFF0000u); \
    const unsigned q1 = cvtpk(s0, s1); \
    const float t0 = s0 - __builtin_bit_cast(float, q1 << 16); \
    const float t1 = s1 - __builtin_bit_cast(float, q1 & 0xFFFF0000u); \
    O0 = (int)q0; O1 = (int)q1; O2 = (int)cvtpk(t0, t1); }

// x staging, coalesced AND bank-swizzled (rule #21 both-sides XOR):
// LDS slot s of row r holds global 16B-granule (s ^ (r&7)). Stage fetches
// granule (lq ^ lt) so the linear gload_lds dest realizes that layout; the
// read XORs again -> identity on data.
#define STAGE_X(c, BUF) { \
    _Pragma("unroll") for (int it = 0; it < 4; ++it) \
        gload_lds16(xsrc + (size_t)it * 8 * DK + (size_t)(c) * 32, \
                    &xs[w][BUF][it * 256]); }

// Per round: 4 x-stage + 12 B = 16 VMEM (the vmcnt unit).
#define ISSUE_B(BS, c) { \
    _Pragma("unroll") for (int n = 0; n < 4; ++n) \
        _Pragma("unroll") for (int p = 0; p < 3; ++p) \
            BS[n][p] = *(const i32x4*)(wbase + ((size_t)(c) * 12 + n * 3 + p) * 512); }

// A-frags from LDS with the inverse swizzle on the granule slot.
#define CONV_LDS(BUF) { \
    _Pragma("unroll") for (int m = 0; m < 2; ++m) { \
        const int row = rr + 16 * m; \
        const int sw  = row & 7; \
        const float4 xa0 = *(const float4*)&xs[w][BUF][row * 32 + (((g * 2 + 0) ^ sw) << 2)]; \
        const float4 xa1 = *(const float4*)&xs[w][BUF][row * 32 + (((g * 2 + 1) ^ sw) << 2)]; \
        SPLIT2(xa0.x, xa0.y, A[m][0].x, A[m][1].x, A[m][2].x); \
        SPLIT2(xa0.z, xa0.w, A[m][0].y, A[m][1].y, A[m][2].y); \
        SPLIT2(xa1.x, xa1.y, A[m][0].z, A[m][1].z, A[m][2].z); \
        SPLIT2(xa1.z, xa1.w, A[m][0].w, A[m][1].w, A[m][2].w); } }

#define MFMA_TERM(pa, pb, BS) { \
    _Pragma("unroll") for (int m = 0; m < 2; ++m) \
        _Pragma("unroll") for (int n = 0; n < 4; ++n) \
            acc[m][n] = __builtin_amdgcn_mfma_f32_16x16x32_bf16( \
                __builtin_bit_cast(s16x8, A[m][pa]), \
                __builtin_bit_cast(s16x8, BS[n][pb]), acc[m][n], 0, 0, 0); }

// 6 terms: (0,0),(0,1),(1,0),(1,1),(0,2),(2,0) -> logit exact to ~2^-24 rel
#define MFMA_ALL(BS) \
    MFMA_TERM(0, 0, BS) MFMA_TERM(0, 1, BS) MFMA_TERM(1, 0, BS) \
    MFMA_TERM(1, 1, BS) MFMA_TERM(0, 2, BS) MFMA_TERM(2, 0, BS)

// Steady phase: 32 VMEM outstanding (rounds c, c+1); vmcnt(16) retires round c
// (x-stage LDS writes included). No barriers: buffers are wave-private.
#define PHASE(BS, c, NCNT, DO_ISSUE) { \
    asm volatile("s_waitcnt vmcnt(" #NCNT ")" ::: "memory"); \
    __builtin_amdgcn_sched_barrier(0); \
    CONV_LDS((c) & 1); \
    MFMA_ALL(BS); \
    if (DO_ISSUE) { STAGE_X((c) + 2, (c) & 1); ISSUE_B(BS, (c) + 2); } \
    __builtin_amdgcn_sched_barrier(0); }

__global__ __launch_bounds__(256, 2) void topk_router_kernel(
    const float* __restrict__ x,            // [NTOK][DK] fp32
    const unsigned short* __restrict__ ws,  // packed B frags (768 KB)
    float* __restrict__ out)                // [NTOK*2] idx (as float) ++ [NTOK*2] w
{
    // xs: wave-private x staging [4 waves][2 bufs][32 tok x 32 k] = 32 KB.
    // lg overlays the same smem after the epilogue barrier (8704 floats).
    __shared__ float smem[8704];
    float (*xs)[2][1024] = (float (*)[2][1024])smem;
    float (*lg)[32][68]  = (float (*)[32][68])smem;

    const int tid  = threadIdx.x;
    const int w    = tid >> 6;              // wave 0..3 == K-quarter
    const int lane = tid & 63;
    const int rr   = lane & 15;
    const int g    = lane >> 4;
    const int tok0 = blockIdx.x * 32;

    // staging lanes: row lt (+8*it), slot lq; pre-swizzled source granule lq^lt
    const int lt = lane >> 3;
    const int lq = lane & 7;
    const float* xsrc = x + (size_t)(tok0 + lt) * DK + w * 512 + ((lq ^ lt) * 4);
    // B: packed frags for this wave's K-quarter; 1 KB contiguous per frag.
    const unsigned short* wbase = ws + (size_t)w * 98304 + (size_t)lane * 8;

    f32x4 acc[2][4];
    #pragma unroll
    for (int m = 0; m < 2; ++m)
        #pragma unroll
        for (int n = 0; n < 4; ++n) acc[m][n] = (f32x4){0.f, 0.f, 0.f, 0.f};

    i32x4 B0[4][3], B1[4][3];
    i32x4 A[2][3];

    // ---- prologue: rounds 0,1 in flight (16 VMEM each) ----
    STAGE_X(0, 0); ISSUE_B(B0, 0);
    STAGE_X(1, 1); ISSUE_B(B1, 1);

    // ---- main: rounds 0..13 (issue c+2), tail 14,15 ----
    #pragma unroll 1
    for (int c = 0; c < 14; c += 2) {
        PHASE(B0, c,     16, 1);
        PHASE(B1, c + 1, 16, 1);
    }
    PHASE(B0, 14, 16, 0);
    PHASE(B1, 15,  0, 0);

    // ---- combine 4 K-quarters (the only barriers) ----
    __syncthreads();
    #pragma unroll
    for (int m = 0; m < 2; ++m)
        #pragma unroll
        for (int n = 0; n < 4; ++n)
            #pragma unroll
            for (int r = 0; r < 4; ++r)
                lg[w][m * 16 + g * 4 + r][n * 16 + rr] = acc[m][n][r];
    __syncthreads();

    // ---- top-2 per token: wave w -> tokens w*8..+7, lane = expert ----
    #pragma unroll 1
    for (int t = 0; t < 8; ++t) {
        const int tok = w * 8 + t;
        const float v = lg[0][tok][lane] + lg[1][tok][lane]
                      + lg[2][tok][lane] + lg[3][tok][lane];

        // top-1 (tie -> lower index, matching lax.top_k)
        float m1 = v; int i1 = lane;
        #pragma unroll
        for (int off = 32; off > 0; off >>= 1) {
            float ov = __shfl_xor(m1, off);
            int   oi = __shfl_xor(i1, off);
            if (ov > m1 || (ov == m1 && oi < i1)) { m1 = ov; i1 = oi; }
        }
        // top-2: mask out winner
        float m2 = (lane == i1) ? -INFINITY : v; int i2 = lane;
        #pragma unroll
        for (int off = 32; off > 0; off >>= 1) {
            float ov = __shfl_xor(m2, off);
            int   oi = __shfl_xor(i2, off);
            if (ov > m2 || (ov == m2 && oi < i2)) { m2 = ov; i2 = oi; }
        }

        if (lane == 0) {
            const int gtok = tok0 + tok;
            // softmax denom cancels: w1 = 1/(1+e^{l2-l1}), w2 = 1 - w1
            const float e  = expf(m2 - m1);
            const float w1 = 1.0f / (1.0f + e);
            const float w2 = e / (1.0f + e);
            out[gtok * 2 + 0] = (float)i1;
            out[gtok * 2 + 1] = (float)i2;
            out[NTOK * 2 + gtok * 2 + 0] = w1;
            out[NTOK * 2 + gtok * 2 + 1] = w2;
        }
    }
}

extern "C" void kernel_launch(void* const* d_in, const int* in_sizes, int n_in,
                              void* d_out, int out_size, void* d_ws, size_t ws_size,
                              hipStream_t stream) {
    const float* x  = (const float*)d_in[0];
    const float* Wg = (const float*)d_in[1];
    float* out = (float*)d_out;
    unsigned short* ws = (unsigned short*)d_ws;   // 768 KB packed B
    hipLaunchKernelGGL(wsplit_pack, dim3(64), dim3(256), 0, stream, Wg, ws);
    // 512 blocks x 256 thr = 2048 waves (2/SIMD): coalesced+swizzled x via LDS,
    // packed B in registers, 2-deep counted-vmcnt pipeline, no in-loop barriers.
    hipLaunchKernelGGL(topk_router_kernel, dim3(NTOK / 32), dim3(256), 0, stream,
                       x, ws, out);
}